// Round 11
// baseline (587.068 us; speedup 1.0000x reference)
//
#include <hip/hip_runtime.h>
#include <hip/hip_bf16.h>
#include <stdint.h>

// ---------------------------------------------------------------------------
// LSTM cell, fused as one bf16 MFMA GEMM:
//   A  = [input | hidden]            : [16384][2048]  (bf16, packed in ws)
//   W  = [Wx[g] | Wh[g]] per gate g  : [4096][2048]   (bf16, packed in ws, [N][K])
//   pre[g][b][s] = sum_k A[b][k] * W[g*1024+s][k] + bias[g][s]
//
// Round 11: W off LDS. Accounting (m134: ds_read_b128 ~12cyc/wave-read,
// per-CU pipe): every round since r6 sat at its LDS-read ceiling
// (r6 0.625 reads/MFMA -> 246us model vs 290 meas; r10 0.5 + conflicts ->
// 255 vs 345). Changes:
//   * W fragments are wave-private and L2-resident (per-XCD W set 2MB with
//     col-major XCD remap) -> load global->register directly. LDS holds
//     only A: reads/MFMA = 0.25 -> LDS ~96us, under MFMA floor (131us);
//     W via L2 ~125us on the VMEM pipe; pipes overlap.
//   * LDS = 2 x 8KB A ring; 1 GLD16/wave/tile; counted vmcnt(1):
//     queue steady state [D(t+1), W(t+1)x4, D(t+2)] -- W(t+1) issued right
//     after COMPUTE(t) frees w[], D(t+2) after the trailing barrier.
//   * conflict fix (r10's 3.35e7): per-16-lane-phase analysis -> slot must
//     cycle all 4 values per row-parity: slot = lg ^ ((lr>>1)&3) (2
//     lanes/4-bank group = free per m136). Global source pre-swizzled to
//     match (both-sides rule).
//   * regs: 64 acc + 16 w + 16 a + ~25 misc ~ 121 < 128 -> 2 blk/CU
//     ((512,4)). Spill tripwire: WRITE_SIZE must stay ~131MB.
// ---------------------------------------------------------------------------

typedef short bf16x8 __attribute__((ext_vector_type(8)));
typedef float f32x4 __attribute__((ext_vector_type(4)));

#define B_ROWS 16384
#define D_K 2048

__device__ __forceinline__ unsigned short f2bf(float f) {
    unsigned u = __builtin_bit_cast(unsigned, f);
    u += 0x7FFFu + ((u >> 16) & 1u);   // round-to-nearest-even
    return (unsigned short)(u >> 16);
}

__device__ __forceinline__ float sigf(float x) { return 1.0f / (1.0f + __expf(-x)); }
__device__ __forceinline__ float tanhfast(float x) { return 2.0f / (1.0f + __expf(-2.0f * x)) - 1.0f; }

// global -> LDS direct copy, 16B per lane; LDS dest wave-uniform base + lane*16.
#define GLD16(gp, lp)                                                          \
    __builtin_amdgcn_global_load_lds(                                          \
        (const __attribute__((address_space(1))) unsigned int*)(gp),           \
        (__attribute__((address_space(3))) unsigned int*)(lp), 16, 0, 0)

#define FENCE() asm volatile("" ::: "memory")

// --------------------------- pack kernels ----------------------------------

__global__ void pack_A_kernel(const float* __restrict__ x,
                              const float* __restrict__ h,
                              unsigned short* __restrict__ A) {
    const int total = B_ROWS * (D_K / 4);          // vec4 units, 512 per row
    for (int v = blockIdx.x * blockDim.x + threadIdx.x; v < total;
         v += gridDim.x * blockDim.x) {
        const int b = v >> 9;
        const int k0 = (v & 511) << 2;
        const float* src = (k0 < 1024) ? (x + (size_t)b * 1024 + k0)
                                       : (h + (size_t)b * 1024 + (k0 - 1024));
        float4 f = *(const float4*)src;
        unsigned p0 = (unsigned)f2bf(f.x) | ((unsigned)f2bf(f.y) << 16);
        unsigned p1 = (unsigned)f2bf(f.z) | ((unsigned)f2bf(f.w) << 16);
        uint2 o; o.x = p0; o.y = p1;
        *(uint2*)(A + (size_t)v * 4) = o;
    }
}

__global__ void pack_W_kernel(const float* __restrict__ Wx,
                              const float* __restrict__ Wh,
                              unsigned short* __restrict__ W) {
    const int total = 4096 * (D_K / 4);
    for (int v = blockIdx.x * blockDim.x + threadIdx.x; v < total;
         v += gridDim.x * blockDim.x) {
        const int n = v >> 9;                       // n = g*1024 + s
        const int k0 = (v & 511) << 2;
        const float* src = (k0 < 1024) ? (Wx + (size_t)n * 1024 + k0)
                                       : (Wh + (size_t)n * 1024 + (k0 - 1024));
        float4 f = *(const float4*)src;
        unsigned p0 = (unsigned)f2bf(f.x) | ((unsigned)f2bf(f.y) << 16);
        unsigned p1 = (unsigned)f2bf(f.z) | ((unsigned)f2bf(f.w) << 16);
        uint2 o; o.x = p0; o.y = p1;
        *(uint2*)(W + (size_t)v * 4) = o;
    }
}

__global__ void pack_bias_kernel(const float* __restrict__ bx,
                                 const float* __restrict__ bh,
                                 float* __restrict__ bias) {
    int i = blockIdx.x * blockDim.x + threadIdx.x;
    if (i < 4096) bias[i] = bx[i] + bh[i];
}

// --------------------------- fused GEMM ------------------------------------
// Block tile: 128 A-rows x 64 s-cols x 4 gates, BK=32, 64 K-tiles.
// 512 threads = 8 waves 2M x 4N: wave = 64r x 16s x 4g, acc[4][4] f32x4.
// LDS: 2 x 8KB ring, A only; chunk w = rows wid*16..+15; row r: 4 slots of
// 16B, LDS slot s holds global k-slot s ^ ((r>>1)&3).
// W: global->register per wave (rows g*1024+bcol+wc*16+lr, k = kt+lg*8).

__global__ __launch_bounds__(512, 4) void lstm_gemm_kernel(
    const unsigned short* __restrict__ A,     // [16384][2048]
    const unsigned short* __restrict__ W,     // [4096][2048]
    const float* __restrict__ bias,           // [4096]
    const float* __restrict__ cell,           // [16384][1024]
    float* __restrict__ out) {                // new_c then h, each [16384][1024]
    __shared__ __align__(16) unsigned short smem[2][4096];   // 16 KB

    // XCD remap, col-tile-major per XCD: 2048 blocks, 256/XCD = 2 col-tiles
    // x 128 row stripes -> per-XCD W set 2MB (L2-resident), A streams.
    const int bid = blockIdx.x;
    const int wgi = (bid & 7) * 256 + (bid >> 3);
    const int brow = (wgi & 127) << 7;        // 128 row stripes of 128
    const int bcol = (wgi >> 7) << 6;         // 16 col tiles of 64 (s in gate)

    const int tid = threadIdx.x;
    const int wid = tid >> 6;                 // 0..7
    const int lane = tid & 63;
    const int wr = wid >> 2;                  // 0..1: rows wr*64..+64
    const int wc = wid & 3;                   // 0..3: s-cols wc*16..+16
    const int lr = lane & 15, lg = lane >> 4;
    const int l16 = lane >> 2;                // row within the 1KB chunk
    // pre-swizzled global k-slot for staging: LDS slot (lane&3) of row
    // (wid*16 + l16) must hold global slot (lane&3)^((row>>1)&3); bits 1-2
    // of row = (lane>>3)&3.
    const int lk = (((lane & 3) ^ ((lane >> 3) & 3)) << 3);

    f32x4 acc[4][4];
#pragma unroll
    for (int g = 0; g < 4; ++g)
#pragma unroll
        for (int m = 0; m < 4; ++m) acc[g][m] = (f32x4){0.f, 0.f, 0.f, 0.f};

    // A staging source (1 chunk per wave per tile)
    const unsigned short* gpA = A + (size_t)(brow + wid * 16 + l16) * D_K + lk;
    // W row bases (per lane; k advances by +32 elems per tile)
    const unsigned short* gpW[4];
#pragma unroll
    for (int g = 0; g < 4; ++g)
        gpW[g] = W + (size_t)(g * 1024 + bcol + wc * 16 + lr) * D_K + lg * 8;

    bf16x8 w[4];

#define STAGE_A(buf, kt)  GLD16(gpA + (kt), (char*)smem[buf] + wid * 1024)
#define LOADW(kt)                                                              \
    do {                                                                       \
        _Pragma("unroll")                                                      \
        for (int _g = 0; _g < 4; ++_g)                                         \
            w[_g] = *(const bf16x8*)(gpW[_g] + (kt));                          \
    } while (0)

    // read-side slot XOR: lane (lr,lg) reads LDS slot lg^((lr>>1)&3) ->
    // per 16-lane phase: 8 distinct 4-bank groups x 2 lanes (2-way = free).
#define COMPUTE(buf)                                                           \
    do {                                                                       \
        const unsigned short* _sb = smem[buf];                                 \
        const int _sl = ((lg ^ ((lr >> 1) & 3)) << 3);                         \
        bf16x8 a[4];                                                           \
        _Pragma("unroll")                                                      \
        for (int m = 0; m < 4; ++m)                                            \
            a[m] = *(const bf16x8*)&_sb[(wr * 64 + m * 16 + lr) * 32 + _sl];   \
        __builtin_amdgcn_s_setprio(1);                                         \
        _Pragma("unroll")                                                      \
        for (int g = 0; g < 4; ++g) {                                          \
            _Pragma("unroll")                                                  \
            for (int m = 0; m < 4; ++m)                                        \
                acc[g][m] = __builtin_amdgcn_mfma_f32_16x16x32_bf16(           \
                    a[m], w[g], acc[g][m], 0, 0, 0);                           \
        }                                                                      \
        __builtin_amdgcn_s_setprio(0);                                         \
    } while (0)

    // prologue; VMEM queue (oldest first): [W0 x4, D0, D1]
    LOADW(0);
    STAGE_A(0, 0);
    STAGE_A(1, 32);

    // steady state per iter t: vmcnt(1) waits {W(t), D(t)}, leaves D(t+1);
    // compute(t); LOADW(t+1) [w dead]; barrier; STAGE_A(t+2) into the buffer
    // just computed (WAR-safe: all waves passed the barrier).
    for (int t = 0; t < 62; ++t) {
        asm volatile("s_waitcnt vmcnt(1)" ::: "memory");
        __builtin_amdgcn_s_barrier();
        FENCE();
        COMPUTE(t & 1);
        LOADW((t + 1) * 32);
        FENCE();
        __builtin_amdgcn_s_barrier();
        FENCE();
        STAGE_A(t & 1, (t + 2) * 32);
    }
    // t = 62: queue [D62, W62 x4, D63] -> vmcnt(1) leaves D63
    asm volatile("s_waitcnt vmcnt(1)" ::: "memory");
    __builtin_amdgcn_s_barrier();
    FENCE();
    COMPUTE(0);
    LOADW(63 * 32);
    FENCE();
    // t = 63: drain everything
    asm volatile("s_waitcnt vmcnt(0)" ::: "memory");
    __builtin_amdgcn_s_barrier();
    FENCE();
    COMPUTE(1);

#undef STAGE_A
#undef LOADW
#undef COMPUTE

    // fused epilogue: C/D layout col = lane&15, row = (lane>>4)*4 + reg
    float bv[4];
#pragma unroll
    for (int g = 0; g < 4; ++g) bv[g] = bias[(g << 10) + bcol + wc * 16 + lr];

    float* outc = out;
    float* outh = out + (size_t)B_ROWS * 1024;
#pragma unroll
    for (int m = 0; m < 4; ++m) {
#pragma unroll
        for (int r = 0; r < 4; ++r) {
            const int b = brow + wr * 64 + m * 16 + lg * 4 + r;
            const size_t idx = (size_t)b * 1024 + bcol + wc * 16 + lr;
            float pf = acc[0][m][r] + bv[0];
            float pi = acc[1][m][r] + bv[1];
            float pc = acc[2][m][r] + bv[2];
            float po = acc[3][m][r] + bv[3];
            float cl = cell[idx];
            float nc = cl * sigf(pf) + sigf(pi) * tanhfast(pc);
            outc[idx] = nc;
            outh[idx] = tanhfast(nc) * sigf(po);
        }
    }
}

// ------------------- fp32 fallback (ws too small; slow but correct) --------

__global__ void lstm_naive_kernel(const float* __restrict__ x,
                                  const float* __restrict__ cell,
                                  const float* __restrict__ h,
                                  const float* __restrict__ Wx,
                                  const float* __restrict__ bx,
                                  const float* __restrict__ Wh,
                                  const float* __restrict__ bh,
                                  float* __restrict__ out) {
    int idx = blockIdx.x * blockDim.x + threadIdx.x;
    if (idx >= B_ROWS * 1024) return;
    int b = idx >> 10, s = idx & 1023;
    const float* xr = x + (size_t)b * 1024;
    const float* hr = h + (size_t)b * 1024;
    float pre[4];
#pragma unroll
    for (int g = 0; g < 4; ++g) {
        float acc = bx[(g << 10) + s] + bh[(g << 10) + s];
        const float* wx = Wx + ((size_t)(g << 10) + s) * 1024;
        const float* wh = Wh + ((size_t)(g << 10) + s) * 1024;
        for (int k = 0; k < 1024; ++k) acc += xr[k] * wx[k] + hr[k] * wh[k];
        pre[g] = acc;
    }
    float nc = cell[idx] * sigf(pre[0]) + sigf(pre[1]) * tanhfast(pre[2]);
    out[idx] = nc;
    out[(size_t)B_ROWS * 1024 + idx] = tanhfast(nc) * sigf(pre[3]);
}

// ---------------------------------------------------------------------------

extern "C" void kernel_launch(void* const* d_in, const int* in_sizes, int n_in,
                              void* d_out, int out_size, void* d_ws, size_t ws_size,
                              hipStream_t stream) {
    const float* x    = (const float*)d_in[0];
    const float* cell = (const float*)d_in[1];
    const float* hid  = (const float*)d_in[2];
    const float* Wx   = (const float*)d_in[3];
    const float* bx   = (const float*)d_in[4];
    const float* Wh   = (const float*)d_in[5];
    const float* bh   = (const float*)d_in[6];
    float* out = (float*)d_out;

    const size_t szA = (size_t)B_ROWS * D_K * 2;    // 64 MB
    const size_t szW = (size_t)4096 * D_K * 2;      // 16 MB
    const size_t szB = 4096 * 4;
    if (ws_size < szA + szW + szB) {
        lstm_naive_kernel<<<(B_ROWS * 1024) / 256, 256, 0, stream>>>(
            x, cell, hid, Wx, bx, Wh, bh, out);
        return;
    }

    unsigned short* Ab = (unsigned short*)d_ws;
    unsigned short* Wb = (unsigned short*)((char*)d_ws + szA);
    float* bias = (float*)((char*)d_ws + szA + szW);

    pack_A_kernel<<<8192, 256, 0, stream>>>(x, hid, Ab);
    pack_W_kernel<<<2048, 256, 0, stream>>>(Wx, Wh, Wb);
    pack_bias_kernel<<<16, 256, 0, stream>>>(bx, bh, bias);

    lstm_gemm_kernel<<<2048, 512, 0, stream>>>(Ab, Wb, bias, cell, out);
}

// Round 12
// 369.113 us; speedup vs baseline: 1.5905x; 1.5905x over previous
//
#include <hip/hip_runtime.h>
#include <hip/hip_bf16.h>
#include <stdint.h>

// ---------------------------------------------------------------------------
// LSTM cell, fused as one bf16 MFMA GEMM:
//   A  = [input | hidden]            : [16384][2048]  (bf16, packed in ws)
//   W  = [Wx[g] | Wh[g]] per gate g  : [4096][2048]   (bf16, packed in ws, [N][K])
//   pre[g][b][s] = sum_k A[b][k] * W[g*1024+s][k] + bias[g][s]
//
// Round 12 = r10's structure + r11's HW-verified swizzle (single variable
// change vs r10). Evidence: r10 {2-deep ring, 2 blk/CU, ratio-0.5 reuse}
// measured 345us WITH 3.35e7 conflict cycles (its swizzle was 4-way
// conflicted); r11 verified slot = lg^((lr>>1)&3) + pre-swizzled source
// (lane&3)^((lane>>3)&3) gives ZERO conflicts. r11 also falsified
// W-in-registers (586us: 1-deep W pipeline exposes scattered-load latency
// every tile) -- W stays in LDS.
//   * wave tile 64r x 16s x 4g -> acc[4][4] f32x4 = 64 f32; block tile
//     128r x 64s x 4g; BK=32 -> 24KB/tile; 2-deep ring = 48KB -> 2 blk/CU.
//   * per tile: STAGE next (3 GLD16) -> vmcnt(3) -> barrier -> 8 ds_read +
//     16 MFMA (setprio) -> barrier. 1-tile prefetch x 2-block TLP covers
//     latency.
//   * LDS model: 16.78M MFMA x 0.5 reads / 256 CU x 12cyc ~ 164us + 27us
//     DMA writes; MFMA floor 132us.
// ---------------------------------------------------------------------------

typedef short bf16x8 __attribute__((ext_vector_type(8)));
typedef float f32x4 __attribute__((ext_vector_type(4)));

#define B_ROWS 16384
#define D_K 2048

__device__ __forceinline__ unsigned short f2bf(float f) {
    unsigned u = __builtin_bit_cast(unsigned, f);
    u += 0x7FFFu + ((u >> 16) & 1u);   // round-to-nearest-even
    return (unsigned short)(u >> 16);
}

__device__ __forceinline__ float sigf(float x) { return 1.0f / (1.0f + __expf(-x)); }
__device__ __forceinline__ float tanhfast(float x) { return 2.0f / (1.0f + __expf(-2.0f * x)) - 1.0f; }

// global -> LDS direct copy, 16B per lane; LDS dest wave-uniform base + lane*16.
#define GLD16(gp, lp)                                                          \
    __builtin_amdgcn_global_load_lds(                                          \
        (const __attribute__((address_space(1))) unsigned int*)(gp),           \
        (__attribute__((address_space(3))) unsigned int*)(lp), 16, 0, 0)

#define FENCE() asm volatile("" ::: "memory")

// --------------------------- pack kernels ----------------------------------

__global__ void pack_A_kernel(const float* __restrict__ x,
                              const float* __restrict__ h,
                              unsigned short* __restrict__ A) {
    const int total = B_ROWS * (D_K / 4);          // vec4 units, 512 per row
    for (int v = blockIdx.x * blockDim.x + threadIdx.x; v < total;
         v += gridDim.x * blockDim.x) {
        const int b = v >> 9;
        const int k0 = (v & 511) << 2;
        const float* src = (k0 < 1024) ? (x + (size_t)b * 1024 + k0)
                                       : (h + (size_t)b * 1024 + (k0 - 1024));
        float4 f = *(const float4*)src;
        unsigned p0 = (unsigned)f2bf(f.x) | ((unsigned)f2bf(f.y) << 16);
        unsigned p1 = (unsigned)f2bf(f.z) | ((unsigned)f2bf(f.w) << 16);
        uint2 o; o.x = p0; o.y = p1;
        *(uint2*)(A + (size_t)v * 4) = o;
    }
}

__global__ void pack_W_kernel(const float* __restrict__ Wx,
                              const float* __restrict__ Wh,
                              unsigned short* __restrict__ W) {
    const int total = 4096 * (D_K / 4);
    for (int v = blockIdx.x * blockDim.x + threadIdx.x; v < total;
         v += gridDim.x * blockDim.x) {
        const int n = v >> 9;                       // n = g*1024 + s
        const int k0 = (v & 511) << 2;
        const float* src = (k0 < 1024) ? (Wx + (size_t)n * 1024 + k0)
                                       : (Wh + (size_t)n * 1024 + (k0 - 1024));
        float4 f = *(const float4*)src;
        unsigned p0 = (unsigned)f2bf(f.x) | ((unsigned)f2bf(f.y) << 16);
        unsigned p1 = (unsigned)f2bf(f.z) | ((unsigned)f2bf(f.w) << 16);
        uint2 o; o.x = p0; o.y = p1;
        *(uint2*)(W + (size_t)v * 4) = o;
    }
}

__global__ void pack_bias_kernel(const float* __restrict__ bx,
                                 const float* __restrict__ bh,
                                 float* __restrict__ bias) {
    int i = blockIdx.x * blockDim.x + threadIdx.x;
    if (i < 4096) bias[i] = bx[i] + bh[i];
}

// --------------------------- fused GEMM ------------------------------------
// Block tile: 128 A-rows x 64 s-cols x 4 gates, BK=32, 64 K-tiles.
// 512 threads = 8 waves 2M x 4N: wave = 64r x 16s x 4g, acc[4][4] f32x4.
// LDS ring: 2 buffers x 24KB; buffer = 24 chunks of 1KB (A: 0..7, W: 8..23);
// chunk = 16 rows x 32 k-elems; row r: LDS slot s holds global k-slot
// s ^ ((r>>1)&3)  [r11 HW-verified: 0 bank conflicts].

__global__ __launch_bounds__(512, 4) void lstm_gemm_kernel(
    const unsigned short* __restrict__ A,     // [16384][2048]
    const unsigned short* __restrict__ W,     // [4096][2048]
    const float* __restrict__ bias,           // [4096]
    const float* __restrict__ cell,           // [16384][1024]
    float* __restrict__ out) {                // new_c then h, each [16384][1024]
    __shared__ __align__(16) unsigned short smem[2][12288];   // 48 KB

    // XCD remap, col-tile-major per XCD: 2048 blocks, 256/XCD = 2 col-tiles
    // x 128 row stripes -> per-XCD W set 2MB (L2-resident), A streams.
    const int bid = blockIdx.x;
    const int wgi = (bid & 7) * 256 + (bid >> 3);
    const int brow = (wgi & 127) << 7;        // 128 row stripes of 128
    const int bcol = (wgi >> 7) << 6;         // 16 col tiles of 64 (s in gate)

    const int tid = threadIdx.x;
    const int wid = tid >> 6;                 // 0..7
    const int lane = tid & 63;
    const int wr = wid >> 2;                  // 0..1: rows wr*64..+64
    const int wc = wid & 3;                   // 0..3: s-cols wc*16..+16
    const int lr = lane & 15, lg = lane >> 4;
    const int l16 = lane >> 2;                // row within a 1KB chunk (16 rows)
    // pre-swizzled global k-slot [r11-verified]: LDS slot (lane&3) of row
    // l16 holds global slot (lane&3)^((l16>>1)&3); (l16>>1)&3 == (lane>>3)&3.
    const int lk = (((lane & 3) ^ ((lane >> 3) & 3)) << 3);

    f32x4 acc[4][4];
#pragma unroll
    for (int g = 0; g < 4; ++g)
#pragma unroll
        for (int m = 0; m < 4; ++m) acc[g][m] = (f32x4){0.f, 0.f, 0.f, 0.f};

    // staging sources: thread stages 3 chunks: c = wid*3+i (A: c<8, W: c>=8)
    const unsigned short* gp[3];
#pragma unroll
    for (int i = 0; i < 3; ++i) {
        const int c = wid * 3 + i;
        if (c < 8) {
            gp[i] = A + (size_t)(brow + c * 16 + l16) * D_K + lk;
        } else {
            const int cw = c - 8;             // 0..15: gate = cw>>2, s-grp = cw&3
            gp[i] = W + (size_t)((cw >> 2) * 1024 + bcol + (cw & 3) * 16 + l16) * D_K + lk;
        }
    }

#define STAGE(buf, kt)                                                         \
    do {                                                                       \
        char* _d = (char*)smem[buf] + (wid * 3) * 1024;                        \
        _Pragma("unroll")                                                      \
        for (int _i = 0; _i < 3; ++_i) GLD16(gp[_i] + (kt), _d + _i * 1024);   \
    } while (0)

    // read-side slot XOR [r11-verified]: lane (lr,lg) reads slot
    // lg^((lr>>1)&3) -> 2 lanes per 4-bank group (free, m136).
#define COMPUTE(buf)                                                           \
    do {                                                                       \
        const unsigned short* _sb = smem[buf];                                 \
        const int _sl = ((lg ^ ((lr >> 1) & 3)) << 3);                         \
        bf16x8 a[4], w[4];                                                     \
        _Pragma("unroll")                                                      \
        for (int m = 0; m < 4; ++m)                                            \
            a[m] = *(const bf16x8*)&_sb[(wr * 4 + m) * 512 + lr * 32 + _sl];   \
        _Pragma("unroll")                                                      \
        for (int g = 0; g < 4; ++g)                                            \
            w[g] = *(const bf16x8*)&_sb[(8 + g * 4 + wc) * 512 + lr * 32 + _sl]; \
        __builtin_amdgcn_s_setprio(1);                                         \
        _Pragma("unroll")                                                      \
        for (int g = 0; g < 4; ++g) {                                          \
            _Pragma("unroll")                                                  \
            for (int m = 0; m < 4; ++m)                                        \
                acc[g][m] = __builtin_amdgcn_mfma_f32_16x16x32_bf16(           \
                    a[m], w[g], acc[g][m], 0, 0, 0);                           \
        }                                                                      \
        __builtin_amdgcn_s_setprio(0);                                         \
    } while (0)

    // prologue: stage tile 0
    STAGE(0, 0);

    // main loop: stage t+1, wait own tile (6 in flight -> vmcnt(3)),
    // barrier, compute, barrier (WAR: next STAGE overwrites buf[t+1&1],
    // last read two barriers ago).
    for (int t = 0; t < 63; ++t) {
        STAGE((t + 1) & 1, (t + 1) * 32);
        asm volatile("s_waitcnt vmcnt(3)" ::: "memory");
        __builtin_amdgcn_s_barrier();
        FENCE();
        COMPUTE(t & 1);
        FENCE();
        __builtin_amdgcn_s_barrier();
        FENCE();
    }
    // tail: tile 63
    asm volatile("s_waitcnt vmcnt(0)" ::: "memory");
    __builtin_amdgcn_s_barrier();
    FENCE();
    COMPUTE(1);

#undef STAGE
#undef COMPUTE

    // fused epilogue: C/D layout col = lane&15, row = (lane>>4)*4 + reg
    float bv[4];
#pragma unroll
    for (int g = 0; g < 4; ++g) bv[g] = bias[(g << 10) + bcol + wc * 16 + lr];

    float* outc = out;
    float* outh = out + (size_t)B_ROWS * 1024;
#pragma unroll
    for (int m = 0; m < 4; ++m) {
#pragma unroll
        for (int r = 0; r < 4; ++r) {
            const int b = brow + wr * 64 + m * 16 + lg * 4 + r;
            const size_t idx = (size_t)b * 1024 + bcol + wc * 16 + lr;
            float pf = acc[0][m][r] + bv[0];
            float pi = acc[1][m][r] + bv[1];
            float pc = acc[2][m][r] + bv[2];
            float po = acc[3][m][r] + bv[3];
            float cl = cell[idx];
            float nc = cl * sigf(pf) + sigf(pi) * tanhfast(pc);
            outc[idx] = nc;
            outh[idx] = tanhfast(nc) * sigf(po);
        }
    }
}

// ------------------- fp32 fallback (ws too small; slow but correct) --------

__global__ void lstm_naive_kernel(const float* __restrict__ x,
                                  const float* __restrict__ cell,
                                  const float* __restrict__ h,
                                  const float* __restrict__ Wx,
                                  const float* __restrict__ bx,
                                  const float* __restrict__ Wh,
                                  const float* __restrict__ bh,
                                  float* __restrict__ out) {
    int idx = blockIdx.x * blockDim.x + threadIdx.x;
    if (idx >= B_ROWS * 1024) return;
    int b = idx >> 10, s = idx & 1023;
    const float* xr = x + (size_t)b * 1024;
    const float* hr = h + (size_t)b * 1024;
    float pre[4];
#pragma unroll
    for (int g = 0; g < 4; ++g) {
        float acc = bx[(g << 10) + s] + bh[(g << 10) + s];
        const float* wx = Wx + ((size_t)(g << 10) + s) * 1024;
        const float* wh = Wh + ((size_t)(g << 10) + s) * 1024;
        for (int k = 0; k < 1024; ++k) acc += xr[k] * wx[k] + hr[k] * wh[k];
        pre[g] = acc;
    }
    float nc = cell[idx] * sigf(pre[0]) + sigf(pre[1]) * tanhfast(pre[2]);
    out[idx] = nc;
    out[(size_t)B_ROWS * 1024 + idx] = tanhfast(nc) * sigf(pre[3]);
}

// ---------------------------------------------------------------------------

extern "C" void kernel_launch(void* const* d_in, const int* in_sizes, int n_in,
                              void* d_out, int out_size, void* d_ws, size_t ws_size,
                              hipStream_t stream) {
    const float* x    = (const float*)d_in[0];
    const float* cell = (const float*)d_in[1];
    const float* hid  = (const float*)d_in[2];
    const float* Wx   = (const float*)d_in[3];
    const float* bx   = (const float*)d_in[4];
    const float* Wh   = (const float*)d_in[5];
    const float* bh   = (const float*)d_in[6];
    float* out = (float*)d_out;

    const size_t szA = (size_t)B_ROWS * D_K * 2;    // 64 MB
    const size_t szW = (size_t)4096 * D_K * 2;      // 16 MB
    const size_t szB = 4096 * 4;
    if (ws_size < szA + szW + szB) {
        lstm_naive_kernel<<<(B_ROWS * 1024) / 256, 256, 0, stream>>>(
            x, cell, hid, Wx, bx, Wh, bh, out);
        return;
    }

    unsigned short* Ab = (unsigned short*)d_ws;
    unsigned short* Wb = (unsigned short*)((char*)d_ws + szA);
    float* bias = (float*)((char*)d_ws + szA + szW);

    pack_A_kernel<<<8192, 256, 0, stream>>>(x, hid, Ab);
    pack_W_kernel<<<2048, 256, 0, stream>>>(Wx, Wh, Wb);
    pack_bias_kernel<<<16, 256, 0, stream>>>(bx, bh, bias);

    lstm_gemm_kernel<<<2048, 512, 0, stream>>>(Ab, Wb, bias, cell, out);
}

// Round 13
// 312.201 us; speedup vs baseline: 1.8804x; 1.1823x over previous
//
#include <hip/hip_runtime.h>
#include <hip/hip_bf16.h>
#include <stdint.h>

// ---------------------------------------------------------------------------
// LSTM cell, fused as one bf16 MFMA GEMM:
//   A  = [input | hidden]            : [16384][2048]  (bf16, packed in ws)
//   W  = [Wx[g] | Wh[g]] per gate g  : [4096][2048]   (bf16, packed in ws, [N][K])
//   pre[g][b][s] = sum_k A[b][k] * W[g*1024+s][k] + bias[g][s]
//
// Round 13 = r6 champion structure (290us GEMM) + ONE change: wave->fragment
// mapping 32r x 32s -> 64r x 16s per gate (wr=wid>>2, wc=wid&3).
//   * reads/MFMA: r6 was 2kk x (2a + 8w) = 20 reads / 32 MFMA (0.625);
//     now 2kk x (4a + 4w) = 16 / 32 (0.5) -- 20% fewer LDS-read cycles
//     (205 -> 164us model per CU) at identical LDS footprint & schedule.
//   * everything else byte-identical to r6: BK=64 single-buffer 48KB,
//     GLD16 staging (6 chunks/wave), explicit vmcnt(0) + __syncthreads,
//     verified XOR swizzle (0 conflicts), XCD remap, (512,2), 2 blk/CU.
// Post-mortem r12: swizzle fix verified (conflicts 3.35e7 -> 0) but time
// unchanged -> conflicts weren't binding; the r7-r12 pipelining family
// loses more to per-iteration sync than it gains (64 iters x 2 barriers).
// ---------------------------------------------------------------------------

typedef short bf16x8 __attribute__((ext_vector_type(8)));
typedef float f32x4 __attribute__((ext_vector_type(4)));

#define B_ROWS 16384
#define D_K 2048

__device__ __forceinline__ unsigned short f2bf(float f) {
    unsigned u = __builtin_bit_cast(unsigned, f);
    u += 0x7FFFu + ((u >> 16) & 1u);   // round-to-nearest-even
    return (unsigned short)(u >> 16);
}

__device__ __forceinline__ float sigf(float x) { return 1.0f / (1.0f + __expf(-x)); }
__device__ __forceinline__ float tanhfast(float x) { return 2.0f / (1.0f + __expf(-2.0f * x)) - 1.0f; }

// global -> LDS direct copy, 16B per lane; LDS dest wave-uniform base + lane*16.
#define GLD16(gp, lp)                                                          \
    __builtin_amdgcn_global_load_lds(                                          \
        (const __attribute__((address_space(1))) unsigned int*)(gp),           \
        (__attribute__((address_space(3))) unsigned int*)(lp), 16, 0, 0)

// --------------------------- pack kernels ----------------------------------

__global__ void pack_A_kernel(const float* __restrict__ x,
                              const float* __restrict__ h,
                              unsigned short* __restrict__ A) {
    const int total = B_ROWS * (D_K / 4);          // vec4 units, 512 per row
    for (int v = blockIdx.x * blockDim.x + threadIdx.x; v < total;
         v += gridDim.x * blockDim.x) {
        const int b = v >> 9;
        const int k0 = (v & 511) << 2;
        const float* src = (k0 < 1024) ? (x + (size_t)b * 1024 + k0)
                                       : (h + (size_t)b * 1024 + (k0 - 1024));
        float4 f = *(const float4*)src;
        unsigned p0 = (unsigned)f2bf(f.x) | ((unsigned)f2bf(f.y) << 16);
        unsigned p1 = (unsigned)f2bf(f.z) | ((unsigned)f2bf(f.w) << 16);
        uint2 o; o.x = p0; o.y = p1;
        *(uint2*)(A + (size_t)v * 4) = o;
    }
}

__global__ void pack_W_kernel(const float* __restrict__ Wx,
                              const float* __restrict__ Wh,
                              unsigned short* __restrict__ W) {
    const int total = 4096 * (D_K / 4);
    for (int v = blockIdx.x * blockDim.x + threadIdx.x; v < total;
         v += gridDim.x * blockDim.x) {
        const int n = v >> 9;                       // n = g*1024 + s
        const int k0 = (v & 511) << 2;
        const float* src = (k0 < 1024) ? (Wx + (size_t)n * 1024 + k0)
                                       : (Wh + (size_t)n * 1024 + (k0 - 1024));
        float4 f = *(const float4*)src;
        unsigned p0 = (unsigned)f2bf(f.x) | ((unsigned)f2bf(f.y) << 16);
        unsigned p1 = (unsigned)f2bf(f.z) | ((unsigned)f2bf(f.w) << 16);
        uint2 o; o.x = p0; o.y = p1;
        *(uint2*)(W + (size_t)v * 4) = o;
    }
}

__global__ void pack_bias_kernel(const float* __restrict__ bx,
                                 const float* __restrict__ bh,
                                 float* __restrict__ bias) {
    int i = blockIdx.x * blockDim.x + threadIdx.x;
    if (i < 4096) bias[i] = bx[i] + bh[i];
}

// --------------------------- fused GEMM ------------------------------------
// Tile: BM=128 rows (b), BN=64 cols (s) x 4 gates, BK=64.
// 512 threads = 8 waves 2M x 4N: wave = 64r x 16s x 4g -> acc[4][4] f32x4.

__global__ __launch_bounds__(512, 2) void lstm_gemm_kernel(
    const unsigned short* __restrict__ A,     // [16384][2048]
    const unsigned short* __restrict__ W,     // [4096][2048]
    const float* __restrict__ bias,           // [4096]
    const float* __restrict__ cell,           // [16384][1024]
    float* __restrict__ out) {                // new_c then h, each [16384][1024]
    // 48 chunks of 1KB; chunk c holds 8 rows x 64 elems (A: 0..15, W: 16..47)
    __shared__ __align__(16) unsigned short smem[24576];

    // XCD-aware remap: 2048 blocks, 8 XCDs, 256 blocks/XCD (bijective).
    const int bid = blockIdx.x;
    const int wg = (bid & 7) * 256 + (bid >> 3);
    const int brow = (wg >> 4) << 7;          // row stripe * 128
    const int bcol = (wg & 15) << 6;          // col tile * 64

    const int tid = threadIdx.x;
    const int wid = tid >> 6;                 // 0..7
    const int lane = tid & 63;
    const int wr = wid >> 2;                  // 0..1: rows wr*64..+64
    const int wc = wid & 3;                   // 0..3: s-cols wc*16..+16
    const int lr = lane & 15, lg = lane >> 4;
    const int l8 = lane >> 3;                 // row within a 1KB staging chunk
    // PRE-SWIZZLED global column (verified r6: 0 conflicts): linear LDS slot
    // (lane&7) receives global col ((lane&7)^l8)*8.
    const int lcol = (((lane & 7) ^ l8) << 3);

    f32x4 acc[4][4];
#pragma unroll
    for (int g = 0; g < 4; ++g)
#pragma unroll
        for (int m = 0; m < 4; ++m) acc[g][m] = (f32x4){0.f, 0.f, 0.f, 0.f};

    // staging sources: wave w owns chunks w*6..w*6+5 (per-lane addresses)
    const unsigned short* gp[6];
#pragma unroll
    for (int i = 0; i < 6; ++i) {
        const int c = wid * 6 + i;
        if (c < 16) {
            gp[i] = A + (size_t)(brow + c * 8 + l8) * D_K + lcol;
        } else {
            const int cw = c - 16;
            gp[i] = W + (size_t)((cw >> 3) * 1024 + bcol + (cw & 7) * 8 + l8) * D_K + lcol;
        }
    }

    for (int kt = 0; kt < D_K; kt += 64) {
        // direct global->LDS DMA, no staging registers
#pragma unroll
        for (int i = 0; i < 6; ++i)
            GLD16(gp[i] + kt, (char*)smem + (wid * 6 + i) * 1024);
        asm volatile("s_waitcnt vmcnt(0)" ::: "memory");
        __syncthreads();

#pragma unroll
        for (int kk = 0; kk < 2; ++kk) {
            // swizzled k-column (elems); fragment row&7 == lr&7 everywhere
            const int swk = (kk * 32 + lg * 8) ^ ((lr & 7) << 3);
            bf16x8 a[4], w[4];
#pragma unroll
            for (int m = 0; m < 4; ++m)
                a[m] = *(const bf16x8*)&smem[(wr * 64 + m * 16 + lr) * 64 + swk];
#pragma unroll
            for (int g = 0; g < 4; ++g)
                w[g] = *(const bf16x8*)&smem[8192 + (g * 64 + wc * 16 + lr) * 64 + swk];
            __builtin_amdgcn_s_setprio(1);
#pragma unroll
            for (int g = 0; g < 4; ++g) {
#pragma unroll
                for (int m = 0; m < 4; ++m)
                    acc[g][m] = __builtin_amdgcn_mfma_f32_16x16x32_bf16(
                        a[m], w[g], acc[g][m], 0, 0, 0);
            }
            __builtin_amdgcn_s_setprio(0);
        }
        __syncthreads();
    }

    // fused epilogue: C/D layout col = lane&15, row = (lane>>4)*4 + reg
    float bv[4];
#pragma unroll
    for (int g = 0; g < 4; ++g) bv[g] = bias[(g << 10) + bcol + wc * 16 + lr];

    float* outc = out;
    float* outh = out + (size_t)B_ROWS * 1024;
#pragma unroll
    for (int m = 0; m < 4; ++m) {
#pragma unroll
        for (int r = 0; r < 4; ++r) {
            const int b = brow + wr * 64 + m * 16 + lg * 4 + r;
            const size_t idx = (size_t)b * 1024 + bcol + wc * 16 + lr;
            float pf = acc[0][m][r] + bv[0];
            float pi = acc[1][m][r] + bv[1];
            float pc = acc[2][m][r] + bv[2];
            float po = acc[3][m][r] + bv[3];
            float cl = cell[idx];
            float nc = cl * sigf(pf) + sigf(pi) * tanhfast(pc);
            outc[idx] = nc;
            outh[idx] = tanhfast(nc) * sigf(po);
        }
    }
}

// ------------------- fp32 fallback (ws too small; slow but correct) --------

__global__ void lstm_naive_kernel(const float* __restrict__ x,
                                  const float* __restrict__ cell,
                                  const float* __restrict__ h,
                                  const float* __restrict__ Wx,
                                  const float* __restrict__ bx,
                                  const float* __restrict__ Wh,
                                  const float* __restrict__ bh,
                                  float* __restrict__ out) {
    int idx = blockIdx.x * blockDim.x + threadIdx.x;
    if (idx >= B_ROWS * 1024) return;
    int b = idx >> 10, s = idx & 1023;
    const float* xr = x + (size_t)b * 1024;
    const float* hr = h + (size_t)b * 1024;
    float pre[4];
#pragma unroll
    for (int g = 0; g < 4; ++g) {
        float acc = bx[(g << 10) + s] + bh[(g << 10) + s];
        const float* wx = Wx + ((size_t)(g << 10) + s) * 1024;
        const float* wh = Wh + ((size_t)(g << 10) + s) * 1024;
        for (int k = 0; k < 1024; ++k) acc += xr[k] * wx[k] + hr[k] * wh[k];
        pre[g] = acc;
    }
    float nc = cell[idx] * sigf(pre[0]) + sigf(pre[1]) * tanhfast(pre[2]);
    out[idx] = nc;
    out[(size_t)B_ROWS * 1024 + idx] = tanhfast(nc) * sigf(pre[3]);
}

// ---------------------------------------------------------------------------

extern "C" void kernel_launch(void* const* d_in, const int* in_sizes, int n_in,
                              void* d_out, int out_size, void* d_ws, size_t ws_size,
                              hipStream_t stream) {
    const float* x    = (const float*)d_in[0];
    const float* cell = (const float*)d_in[1];
    const float* hid  = (const float*)d_in[2];
    const float* Wx   = (const float*)d_in[3];
    const float* bx   = (const float*)d_in[4];
    const float* Wh   = (const float*)d_in[5];
    const float* bh   = (const float*)d_in[6];
    float* out = (float*)d_out;

    const size_t szA = (size_t)B_ROWS * D_K * 2;    // 64 MB
    const size_t szW = (size_t)4096 * D_K * 2;      // 16 MB
    const size_t szB = 4096 * 4;
    if (ws_size < szA + szW + szB) {
        lstm_naive_kernel<<<(B_ROWS * 1024) / 256, 256, 0, stream>>>(
            x, cell, hid, Wx, bx, Wh, bh, out);
        return;
    }

    unsigned short* Ab = (unsigned short*)d_ws;
    unsigned short* Wb = (unsigned short*)((char*)d_ws + szA);
    float* bias = (float*)((char*)d_ws + szA + szW);

    pack_A_kernel<<<8192, 256, 0, stream>>>(x, hid, Ab);
    pack_W_kernel<<<2048, 256, 0, stream>>>(Wx, Wh, Wb);
    pack_bias_kernel<<<16, 256, 0, stream>>>(bx, bh, bias);

    lstm_gemm_kernel<<<2048, 512, 0, stream>>>(Ab, Wb, bias, cell, out);
}